// Round 1
// 1760.316 us; speedup vs baseline: 1.0430x; 1.0430x over previous
//
#include <hip/hip_runtime.h>
#include <hip/hip_bf16.h>

// PerformerSelfLayer: B=4, N=4096, D=1024, H=16, DH=64, M=256, DFF=4096
#define N_TOK   4096
#define DMODEL  1024
#define NHEADS  16
#define DH      64
#define MFEAT   256
#define DFF     4096
#define BATCH   4
#define ROWS    (BATCH * N_TOK)   // 16384

#define NORMF      0.35355339059327373f  // 64^-0.25
#define HALF_NORM2 0.0625f               // 0.5 * norm^2
#define RATIO      0.0625f               // 256^-0.5
#define EPSK       1e-4f
#define LNEPS      1e-5f

typedef unsigned short ushort_t;
using bfrag = __attribute__((ext_vector_type(8))) short;   // 8 bf16 (4 VGPRs)
using facc  = __attribute__((ext_vector_type(4))) float;   // 4 fp32 acc
using ush8  = __attribute__((ext_vector_type(8))) unsigned short;

__device__ __forceinline__ float b2f(ushort_t u) {
    return __bfloat162float(__builtin_bit_cast(__hip_bfloat16, u));
}
__device__ __forceinline__ ushort_t f2b(float f) {
    return __builtin_bit_cast(ushort_t, __float2bfloat16(f));
}
__device__ __forceinline__ void stC(float* p, float v) { *p = v; }
__device__ __forceinline__ void stC(ushort_t* p, float v) { *p = f2b(v); }

// async global->LDS DMA, 16B per lane. LDS dest must be wave-uniform base + lane*16.
__device__ __forceinline__ void gload_lds16(const void* g, void* l) {
    __builtin_amdgcn_global_load_lds(
        (const __attribute__((address_space(1))) unsigned int*)g,
        (__attribute__((address_space(3))) unsigned int*)l, 16, 0, 0);
}

// order-preserving float->uint key for atomicMax; memset(0) is below any real key
__device__ __forceinline__ unsigned fkey(float f) {
    unsigned u = __float_as_uint(f);
    return (u & 0x80000000u) ? ~u : (u | 0x80000000u);
}
__device__ __forceinline__ float fdec(unsigned k) {
    return (k & 0x80000000u) ? __uint_as_float(k ^ 0x80000000u) : __uint_as_float(~k);
}

// ---------------- fp32 -> bf16 conversion (vectorized)
__global__ __launch_bounds__(256) void cvt_bf16(const float* __restrict__ s,
                                                ushort_t* __restrict__ d, int n4) {
    int i = blockIdx.x * 256 + threadIdx.x;
    if (i >= n4) return;
    float4 v = ((const float4*)s)[i];
    ((ushort4*)d)[i] = make_ushort4(f2b(v.x), f2b(v.y), f2b(v.z), f2b(v.w));
}

// ---------------- bf16 MFMA GEMM: C[M,N] = A[M,K] (bf16) * W[N,K]^T (bf16) + bias
// m97 structure: linear LDS + global_load_lds(16B) staging + XCD-aware tile swizzle
template <int FJ, typename OT>
__global__ __launch_bounds__(256) void gemm_mfma(
    const ushort_t* __restrict__ A, const ushort_t* __restrict__ W,
    const float* __restrict__ bias, OT* __restrict__ C,
    int Nout, int K, int relu)
{
    constexpr int BN = FJ * 32;
    __shared__ short As[128 * 32];
    __shared__ short Ws[BN * 32];
    const int t = threadIdx.x;
    // XCD swizzle: all grids here have nwg % 8 == 0; bijective chunked remap
    const unsigned nwg = gridDim.x * gridDim.y;
    const unsigned flat = blockIdx.y * gridDim.x + blockIdx.x;
    const unsigned cpx = nwg >> 3;
    const unsigned wg = (flat & 7) * cpx + (flat >> 3);
    const int m0 = (int)(wg / gridDim.x) * 128, n0 = (int)(wg % gridDim.x) * BN;
    const int lane = t & 63, wave = t >> 6;
    const int wr = (wave >> 1) * 64, wc = (wave & 1) * (FJ * 16);
    const int lm = lane & 15, kq = (lane >> 4) * 8;
    facc acc[4][FJ];
#pragma unroll
    for (int i = 0; i < 4; ++i)
#pragma unroll
        for (int j = 0; j < FJ; ++j) acc[i][j] = (facc){0.f, 0.f, 0.f, 0.f};

    for (int k0 = 0; k0 < K; k0 += 32) {
#pragma unroll
        for (int it = 0; it < 2; ++it) {
            int ch = t + it * 256;
            int row = ch >> 2, c8 = (ch & 3) * 8;
            gload_lds16(A + (size_t)(m0 + row) * K + k0 + c8, &As[ch * 8]);
        }
#pragma unroll
        for (int it = 0; it < BN / 64; ++it) {
            int ch = t + it * 256;
            int row = ch >> 2, c8 = (ch & 3) * 8;
            gload_lds16(W + (size_t)(n0 + row) * K + k0 + c8, &Ws[ch * 8]);
        }
        __syncthreads();
        bfrag af[4], bf[FJ];
#pragma unroll
        for (int i = 0; i < 4; ++i) af[i] = *(bfrag*)&As[(wr + i * 16 + lm) * 32 + kq];
#pragma unroll
        for (int j = 0; j < FJ; ++j) bf[j] = *(bfrag*)&Ws[(wc + j * 16 + lm) * 32 + kq];
#pragma unroll
        for (int i = 0; i < 4; ++i)
#pragma unroll
            for (int j = 0; j < FJ; ++j)
                acc[i][j] = __builtin_amdgcn_mfma_f32_16x16x32_bf16(af[i], bf[j], acc[i][j], 0, 0, 0);
        __syncthreads();
    }
    const int rq = (lane >> 4) * 4;
#pragma unroll
    for (int i = 0; i < 4; ++i)
#pragma unroll
        for (int j = 0; j < FJ; ++j) {
            int col = n0 + wc + j * 16 + lm;
            float bc = bias[col];
#pragma unroll
            for (int r = 0; r < 4; ++r) {
                int row = m0 + wr + i * 16 + rq + r;
                float v = acc[i][j][r] + bc;
                if (relu) v = fmaxf(v, 0.f);
                stC(C + (size_t)row * Nout + col, v);
            }
        }
}

// ---------------- V_b [4096][1024] -> VT [16][64][4096] (per-head transpose)
__global__ __launch_bounds__(256) void vt_kernel(
    const ushort_t* __restrict__ V, ushort_t* __restrict__ VT)
{
    __shared__ ushort_t tile[64][68];
    const int t = threadIdx.x;
    const int n0 = blockIdx.x * 64, h = blockIdx.y;
#pragma unroll
    for (int i = 0; i < 4; ++i) {
        int idx = t + i * 256;                    // 1024 ushort4 chunks
        int nl = idx >> 4, d4 = (idx & 15) * 4;
        ushort4 v = *(const ushort4*)(V + (size_t)(n0 + nl) * DMODEL + h * DH + d4);
        tile[nl][d4 + 0] = v.x; tile[nl][d4 + 1] = v.y;
        tile[nl][d4 + 2] = v.z; tile[nl][d4 + 3] = v.w;
    }
    __syncthreads();
#pragma unroll
    for (int i = 0; i < 4; ++i) {
        int idx = t + i * 256;
        int d = idx >> 4, n4 = (idx & 15) * 4;
        ushort4 o = make_ushort4(tile[n4][d], tile[n4 + 1][d], tile[n4 + 2][d], tile[n4 + 3][d]);
        *(ushort4*)(VT + (size_t)h * DH * N_TOK + (size_t)d * N_TOK + n0 + n4) = o;
    }
}

// ---------------- diagK[h][n] = sum_dh K[n][h*64+dh]^2  (wave per n, shuffle)
__global__ __launch_bounds__(256) void diagk_kernel(
    const ushort_t* __restrict__ Kb, float* __restrict__ diagK)
{
    const int lane = threadIdx.x & 63, wave = threadIdx.x >> 6;
    const int n = blockIdx.x * 4 + wave;
    const ushort_t* kr = Kb + (size_t)n * DMODEL + lane * 16;
    ush8 a = *(const ush8*)kr;
    ush8 b = *(const ush8*)(kr + 8);
    float s = 0.f;
#pragma unroll
    for (int e = 0; e < 8; ++e) { float x = b2f(a[e]); s += x * x; }
#pragma unroll
    for (int e = 0; e < 8; ++e) { float x = b2f(b[e]); s += x * x; }
    s += __shfl_xor(s, 1);
    s += __shfl_xor(s, 2);
    if ((lane & 3) == 0) diagK[(size_t)(lane >> 2) * N_TOK + n] = s;
}

// ---------------- K-side feature GEMM: acc = proj[m,:] . K[n, h*64:] (K=64, MFMA)
// mode 0: per-h global max -> atomicMax kmax16.  mode 1: exp epilogue -> KP[h][m][n] bf16
__global__ __launch_bounds__(256) void xk_kernel(
    const ushort_t* __restrict__ projBF,   // [256][64]
    const ushort_t* __restrict__ Kb,       // [4096][1024]
    const float* __restrict__ diagK,       // [16][4096]
    unsigned* __restrict__ kmax16,         // [16]
    ushort_t* __restrict__ KP,             // [16][256][4096]
    int mode)
{
    __shared__ short As[128 * 32];
    __shared__ short Ws[128 * 32];
    const int t = threadIdx.x;
    const int m0 = blockIdx.x * 128, n0 = blockIdx.y * 128, h = blockIdx.z;
    const ushort_t* Kh = Kb + h * DH;
    const int lane = t & 63, wave = t >> 6;
    const int wr = (wave >> 1) * 64, wc = (wave & 1) * 64;
    const int lm = lane & 15, kq = (lane >> 4) * 8;
    facc acc[4][4];
#pragma unroll
    for (int i = 0; i < 4; ++i)
#pragma unroll
        for (int j = 0; j < 4; ++j) acc[i][j] = (facc){0.f, 0.f, 0.f, 0.f};

    for (int k0 = 0; k0 < DH; k0 += 32) {
#pragma unroll
        for (int it = 0; it < 2; ++it) {
            int ch = t + it * 256;
            int row = ch >> 2, c8 = (ch & 3) * 8;
            gload_lds16(projBF + (size_t)(m0 + row) * DH + k0 + c8, &As[ch * 8]);
            gload_lds16(Kh + (size_t)(n0 + row) * DMODEL + k0 + c8, &Ws[ch * 8]);
        }
        __syncthreads();
        bfrag af[4], bf[4];
#pragma unroll
        for (int i = 0; i < 4; ++i) af[i] = *(bfrag*)&As[(wr + i * 16 + lm) * 32 + kq];
#pragma unroll
        for (int j = 0; j < 4; ++j) bf[j] = *(bfrag*)&Ws[(wc + j * 16 + lm) * 32 + kq];
#pragma unroll
        for (int i = 0; i < 4; ++i)
#pragma unroll
            for (int j = 0; j < 4; ++j)
                acc[i][j] = __builtin_amdgcn_mfma_f32_16x16x32_bf16(af[i], bf[j], acc[i][j], 0, 0, 0);
        __syncthreads();
    }
    const int rq = (lane >> 4) * 4;
    if (mode == 0) {
        float mx = -1e30f;
#pragma unroll
        for (int i = 0; i < 4; ++i)
#pragma unroll
            for (int j = 0; j < 4; ++j)
#pragma unroll
                for (int r = 0; r < 4; ++r) mx = fmaxf(mx, acc[i][j][r]);
        mx *= NORMF;
#pragma unroll
        for (int o = 32; o >= 1; o >>= 1) mx = fmaxf(mx, __shfl_xor(mx, o));
        if (lane == 0) atomicMax(kmax16 + h, fkey(mx));
    } else {
        const float stab = fdec(kmax16[h]);
        ushort_t* kb = KP + (size_t)h * MFEAT * N_TOK;
#pragma unroll
        for (int j = 0; j < 4; ++j) {
            int n = n0 + wc + j * 16 + lm;
            float dg = HALF_NORM2 * diagK[(size_t)h * N_TOK + n] + stab;
#pragma unroll
            for (int i = 0; i < 4; ++i)
#pragma unroll
                for (int r = 0; r < 4; ++r) {
                    int m = m0 + wr + i * 16 + rq + r;
                    float x = NORMF * acc[i][j][r];
                    kb[(size_t)m * N_TOK + n] = f2b(RATIO * (expf(x - dg) + EPSK));
                }
        }
    }
}

// ---------------- ksum[h*256+m] = sum_n KP[h][m][n]  (wave per row)
__global__ __launch_bounds__(256) void ksum_kernel(
    const ushort_t* __restrict__ KP, float* __restrict__ ksum)
{
    const int lane = threadIdx.x & 63, wave = threadIdx.x >> 6;
    const int row = blockIdx.x * 4 + wave;
    const ushort_t* kr = KP + (size_t)row * N_TOK;
    float s = 0.f;
#pragma unroll
    for (int it = 0; it < 8; ++it) {
        ush8 v = *(const ush8*)(kr + it * 512 + lane * 8);
#pragma unroll
        for (int e = 0; e < 8; ++e) s += b2f(v[e]);
    }
#pragma unroll
    for (int o = 32; o >= 1; o >>= 1) s += __shfl_xor(s, o);
    if (lane == 0) ksum[row] = s;
}

// ---------------- ctx[h][m][d] += sum_{n in chunk} KP[h][m][n] * VT[h][d][n]  (MFMA)
__global__ __launch_bounds__(256) void ctx_mfma(
    const ushort_t* __restrict__ KP, const ushort_t* __restrict__ VT,
    float* __restrict__ ctx)
{
    __shared__ short As[128 * 32];
    __shared__ short Vs[64 * 32];
    const int t = threadIdx.x;
    const int z = blockIdx.x, mh = blockIdx.y, h = blockIdx.z;
    const ushort_t* A = KP + (size_t)h * MFEAT * N_TOK + (size_t)mh * 128 * N_TOK;
    const ushort_t* W = VT + (size_t)h * DH * N_TOK;
    const int lane = t & 63, wave = t >> 6;
    const int wr = (wave >> 1) * 64, wc = (wave & 1) * 32;
    const int lm = lane & 15, kq = (lane >> 4) * 8;
    facc acc[4][2];
#pragma unroll
    for (int i = 0; i < 4; ++i)
#pragma unroll
        for (int j = 0; j < 2; ++j) acc[i][j] = (facc){0.f, 0.f, 0.f, 0.f};

    const int kbeg = z * 512, kend = kbeg + 512;
    for (int k0 = kbeg; k0 < kend; k0 += 32) {
#pragma unroll
        for (int it = 0; it < 2; ++it) {
            int ch = t + it * 256;
            int row = ch >> 2, c8 = (ch & 3) * 8;
            gload_lds16(A + (size_t)row * N_TOK + k0 + c8, &As[ch * 8]);
        }
        {
            int row = t >> 2, c8 = (t & 3) * 8;
            gload_lds16(W + (size_t)row * N_TOK + k0 + c8, &Vs[t * 8]);
        }
        __syncthreads();
        bfrag af[4], bf[2];
#pragma unroll
        for (int i = 0; i < 4; ++i) af[i] = *(bfrag*)&As[(wr + i * 16 + lm) * 32 + kq];
#pragma unroll
        for (int j = 0; j < 2; ++j) bf[j] = *(bfrag*)&Vs[(wc + j * 16 + lm) * 32 + kq];
#pragma unroll
        for (int i = 0; i < 4; ++i)
#pragma unroll
            for (int j = 0; j < 2; ++j)
                acc[i][j] = __builtin_amdgcn_mfma_f32_16x16x32_bf16(af[i], bf[j], acc[i][j], 0, 0, 0);
        __syncthreads();
    }
    const int rq = (lane >> 4) * 4;
    float* cb = ctx + (size_t)h * MFEAT * DH + (size_t)mh * 128 * DH;
#pragma unroll
    for (int i = 0; i < 4; ++i)
#pragma unroll
        for (int j = 0; j < 2; ++j)
#pragma unroll
            for (int r = 0; r < 4; ++r) {
                int m = wr + i * 16 + rq + r;
                int d = wc + j * 16 + lm;
                atomicAdd(cb + (size_t)m * DH + d, acc[i][j][r]);
            }
}

// ---------------- ctx [h][256][64] fp32 -> ctxT [h][64][256] bf16
__global__ __launch_bounds__(256) void ctx_transpose(
    const float* __restrict__ ctx, ushort_t* __restrict__ ctxT)
{
    __shared__ float tile[64][65];
    const int bh = blockIdx.x, t = threadIdx.x;
    const float* cb = ctx + (size_t)bh * MFEAT * DH;
    ushort_t* ob = ctxT + (size_t)bh * DH * MFEAT;
    for (int mb = 0; mb < 4; ++mb) {
#pragma unroll
        for (int i = 0; i < 16; ++i) {
            int idx = t + i * 256;
            tile[idx >> 6][idx & 63] = cb[(size_t)(mb * 64 + (idx >> 6)) * DH + (idx & 63)];
        }
        __syncthreads();
#pragma unroll
        for (int i = 0; i < 16; ++i) {
            int idx = t + i * 256;
            ob[(size_t)(idx >> 6) * MFEAT + mb * 64 + (idx & 63)] = f2b(tile[idx & 63][idx >> 6]);
        }
        __syncthreads();
    }
}

// ---------------- XP[h][n][m] = NORMF * (Q[n,h*64:] . proj[m,:]) — MFMA, K=64
__global__ __launch_bounds__(256) void xp_gemm(
    const float* __restrict__ Q, const ushort_t* __restrict__ projBF,
    ushort_t* __restrict__ XP)
{
    __shared__ short As[128][40];
    __shared__ short Ws[128][40];
    const int t = threadIdx.x;
    const int m0 = blockIdx.x * 128, n0v = blockIdx.y * 128, h = blockIdx.z;
    const float* Qb = Q + h * DH;
    const int lane = t & 63, wave = t >> 6;
    const int wr = (wave >> 1) * 64, wc = (wave & 1) * 64;
    const int lm = lane & 15, kq = (lane >> 4) * 8;
    facc acc[4][4];
#pragma unroll
    for (int i = 0; i < 4; ++i)
#pragma unroll
        for (int j = 0; j < 4; ++j) acc[i][j] = (facc){0.f, 0.f, 0.f, 0.f};

    for (int k0 = 0; k0 < 64; k0 += 32) {
#pragma unroll
        for (int it = 0; it < 4; ++it) {
            int ch = t + it * 256;
            int row = ch >> 3, c4 = (ch & 7) * 4;
            float4 v = *(const float4*)(Qb + (size_t)(n0v + row) * DMODEL + k0 + c4);
            As[row][c4 + 0] = (short)f2b(v.x);
            As[row][c4 + 1] = (short)f2b(v.y);
            As[row][c4 + 2] = (short)f2b(v.z);
            As[row][c4 + 3] = (short)f2b(v.w);
        }
#pragma unroll
        for (int it = 0; it < 2; ++it) {
            int ch = t + it * 256;
            int row = ch >> 2, c8 = (ch & 3) * 8;
            *(uint4*)&Ws[row][c8] = *(const uint4*)(projBF + (size_t)(m0 + row) * DH + k0 + c8);
        }
        __syncthreads();
        bfrag af[4], bf[4];
#pragma unroll
        for (int i = 0; i < 4; ++i) af[i] = *(bfrag*)&As[wr + i * 16 + lm][kq];
#pragma unroll
        for (int j = 0; j < 4; ++j) bf[j] = *(bfrag*)&Ws[wc + j * 16 + lm][kq];
#pragma unroll
        for (int i = 0; i < 4; ++i)
#pragma unroll
            for (int j = 0; j < 4; ++j)
                acc[i][j] = __builtin_amdgcn_mfma_f32_16x16x32_bf16(af[i], bf[j], acc[i][j], 0, 0, 0);
        __syncthreads();
    }
    const int rq = (lane >> 4) * 4;
    ushort_t* xb = XP + (size_t)h * N_TOK * MFEAT;
#pragma unroll
    for (int i = 0; i < 4; ++i)
#pragma unroll
        for (int j = 0; j < 4; ++j) {
            int col = m0 + wc + j * 16 + lm;
#pragma unroll
            for (int r = 0; r < 4; ++r) {
                int row = n0v + wr + i * 16 + rq + r;
                xb[(size_t)row * MFEAT + col] = f2b(NORMF * acc[i][j][r]);
            }
        }
}

// ---------------- per-row q-features: stab/exp -> QP bf16 in-place + denom
__global__ __launch_bounds__(256) void qp_kernel(
    ushort_t* __restrict__ XP, const float* __restrict__ Q,
    const float* __restrict__ ksum, float* __restrict__ denom)
{
    const int lane = threadIdx.x & 63, wave = threadIdx.x >> 6;
    const int row0 = (blockIdx.x * 4 + wave) * 8;
    for (int rr = 0; rr < 8; ++rr) {
        const int row = row0 + rr;
        const int h = row >> 12, n = row & 4095;
        ushort_t* xr = XP + (size_t)row * MFEAT + lane * 4;
        ushort4 xv = *(ushort4*)xr;
        float x0 = b2f(xv.x), x1 = b2f(xv.y), x2 = b2f(xv.z), x3 = b2f(xv.w);
        float qv = Q[(size_t)n * DMODEL + h * DH + lane];
        float ss = qv * qv;
#pragma unroll
        for (int o = 32; o >= 1; o >>= 1) ss += __shfl_xor(ss, o);
        float mx = fmaxf(fmaxf(x0, x1), fmaxf(x2, x3));
#pragma unroll
        for (int o = 32; o >= 1; o >>= 1) mx = fmaxf(mx, __shfl_xor(mx, o));
        const float sh = HALF_NORM2 * ss + mx;
        float p0 = RATIO * (expf(x0 - sh) + EPSK);
        float p1 = RATIO * (expf(x1 - sh) + EPSK);
        float p2 = RATIO * (expf(x2 - sh) + EPSK);
        float p3 = RATIO * (expf(x3 - sh) + EPSK);
        ushort4 pv = make_ushort4(f2b(p0), f2b(p1), f2b(p2), f2b(p3));
        *(ushort4*)xr = pv;
        float4 ks4 = *(const float4*)(ksum + h * MFEAT + lane * 4);
        float dn = b2f(pv.x) * ks4.x + b2f(pv.y) * ks4.y + b2f(pv.z) * ks4.z + b2f(pv.w) * ks4.w;
#pragma unroll
        for (int o = 32; o >= 1; o >>= 1) dn += __shfl_xor(dn, o);
        if (lane == 0) denom[row] = dn;
    }
}

// ---------------- OUT[n][h*64+d] = (QP . ctxT[d]) / denom — MFMA, K=256
__global__ __launch_bounds__(256) void out_gemm(
    const ushort_t* __restrict__ XP, const ushort_t* __restrict__ ctxT,
    const float* __restrict__ denom, ushort_t* __restrict__ OUT)
{
    __shared__ short As[128 * 32];
    __shared__ short Ws[64 * 32];
    const int t = threadIdx.x;
    const int n0 = blockIdx.x * 128, h = blockIdx.y;
    const ushort_t* A = XP + (size_t)h * N_TOK * MFEAT;
    const ushort_t* W = ctxT + (size_t)h * DH * MFEAT;
    const float* dnb = denom + (size_t)h * N_TOK;
    ushort_t* ob = OUT + h * DH;
    const int lane = t & 63, wave = t >> 6;
    const int wr = (wave >> 1) * 64, wc = (wave & 1) * 32;
    const int lm = lane & 15, kq = (lane >> 4) * 8;
    facc acc[4][2];
#pragma unroll
    for (int i = 0; i < 4; ++i)
#pragma unroll
        for (int j = 0; j < 2; ++j) acc[i][j] = (facc){0.f, 0.f, 0.f, 0.f};

    for (int k0 = 0; k0 < MFEAT; k0 += 32) {
#pragma unroll
        for (int it = 0; it < 2; ++it) {
            int ch = t + it * 256;
            int row = ch >> 2, c8 = (ch & 3) * 8;
            gload_lds16(A + (size_t)(n0 + row) * MFEAT + k0 + c8, &As[ch * 8]);
        }
        {
            int row = t >> 2, c8 = (t & 3) * 8;
            gload_lds16(W + (size_t)row * MFEAT + k0 + c8, &Ws[t * 8]);
        }
        __syncthreads();
        bfrag af[4], bf[2];
#pragma unroll
        for (int i = 0; i < 4; ++i) af[i] = *(bfrag*)&As[(wr + i * 16 + lm) * 32 + kq];
#pragma unroll
        for (int j = 0; j < 2; ++j) bf[j] = *(bfrag*)&Ws[(wc + j * 16 + lm) * 32 + kq];
#pragma unroll
        for (int i = 0; i < 4; ++i)
#pragma unroll
            for (int j = 0; j < 2; ++j)
                acc[i][j] = __builtin_amdgcn_mfma_f32_16x16x32_bf16(af[i], bf[j], acc[i][j], 0, 0, 0);
        __syncthreads();
    }
    const int rq = (lane >> 4) * 4;
#pragma unroll
    for (int i = 0; i < 4; ++i)
#pragma unroll
        for (int r = 0; r < 4; ++r) {
            int row = n0 + wr + i * 16 + rq + r;
            float inv = 1.f / dnb[row];
#pragma unroll
            for (int j = 0; j < 2; ++j) {
                int col = wc + j * 16 + lm;
                ob[(size_t)row * DMODEL + col] = f2b(acc[i][j][r] * inv);
            }
        }
}

// ---------------- LayerNorm: out = LN(A + Badd)*g + b; optional bf16 copy
__global__ __launch_bounds__(256) void ln_kernel(
    const float* __restrict__ A, const void* __restrict__ Badd, int badd_bf16,
    const float* __restrict__ g, const float* __restrict__ bb,
    float* __restrict__ out, ushort_t* __restrict__ out_bf)
{
    __shared__ float red[256];
    const int row = blockIdx.x, t = threadIdx.x;
    const float* a = A + (size_t)row * DMODEL;
    float v[4];
    float s = 0.f;
#pragma unroll
    for (int i = 0; i < 4; ++i) {
        int col = t + i * 256;
        float add = badd_bf16 ? b2f(((const ushort_t*)Badd)[(size_t)row * DMODEL + col])
                              : ((const float*)Badd)[(size_t)row * DMODEL + col];
        v[i] = a[col] + add;
        s += v[i];
    }
    red[t] = s;
    __syncthreads();
    for (int st = 128; st > 0; st >>= 1) { if (t < st) red[t] += red[t + st]; __syncthreads(); }
    float mu = red[0] * (1.f / DMODEL);
    __syncthreads();
    float sq = 0.f;
#pragma unroll
    for (int i = 0; i < 4; ++i) { float dlt = v[i] - mu; sq += dlt * dlt; }
    red[t] = sq;
    __syncthreads();
    for (int st = 128; st > 0; st >>= 1) { if (t < st) red[t] += red[t + st]; __syncthreads(); }
    float rstd = rsqrtf(red[0] * (1.f / DMODEL) + LNEPS);
    float* o = out + (size_t)row * DMODEL;
#pragma unroll
    for (int i = 0; i < 4; ++i) {
        int col = t + i * 256;
        float val = (v[i] - mu) * rstd * g[col] + bb[col];
        o[col] = val;
        if (out_bf) out_bf[(size_t)row * DMODEL + col] = f2b(val);
    }
}

extern "C" void kernel_launch(void* const* d_in, const int* in_sizes, int n_in,
                              void* d_out, int out_size, void* d_ws, size_t ws_size,
                              hipStream_t stream)
{
    const float* video = (const float*)d_in[0];
    const float* Wq = (const float*)d_in[1];
    const float* bq = (const float*)d_in[2];
    const float* Wk = (const float*)d_in[3];
    const float* bk = (const float*)d_in[4];
    const float* Wv = (const float*)d_in[5];
    const float* bv = (const float*)d_in[6];
    const float* Wo = (const float*)d_in[7];
    const float* bo = (const float*)d_in[8];
    const float* proj = (const float*)d_in[9];
    const float* W1 = (const float*)d_in[10];
    const float* b1 = (const float*)d_in[11];
    const float* W2 = (const float*)d_in[12];
    const float* b2 = (const float*)d_in[13];
    const float* g2 = (const float*)d_in[14];
    const float* be2 = (const float*)d_in[15];
    const float* g3 = (const float*)d_in[16];
    const float* be3 = (const float*)d_in[17];

    // workspace map (peak ~124 MiB), per-batch pipeline with aliasing:
    //  [0,32M)      videoBF (alive whole loop)
    //  [32M,40M)    K_b bf16        -> XBF_b (after xk passes)
    //  [40M,48M)    V_b bf16        -> F_b (FF2 out)
    //  [48M,56M)    VT_b bf16       -> Y_b (attn@Wo out)
    //  [56M,89.5M)  KP (33.5M)      -> XP (q-side) -> H_b (FFN hidden, 32M)
    //  [89.5M,90.5M) ctx_b fp32 | [90.5,91M) ctxT_b bf16
    //  [91M,92M)    smalls: diagK, ksum, denom, kmax16, projBF
    //  [92M,100M)   OUT_b bf16
    //  [100M,124M)  weights bf16: Wq,Wk,Wv,Wo (2M ea), W1 (8M), W2 (8M)
    //  d_out: Q fp32 (all batches) -> X_b fp32 -> final out
    char* ws = (char*)d_ws;
    const size_t MB = 1048576ull;
    ushort_t* videoBF = (ushort_t*)(ws + 0);
    ushort_t* Kb   = (ushort_t*)(ws + 32 * MB);
    ushort_t* XBFb = (ushort_t*)(ws + 32 * MB);
    ushort_t* Vb   = (ushort_t*)(ws + 40 * MB);
    ushort_t* Fb   = (ushort_t*)(ws + 40 * MB);
    ushort_t* VTb  = (ushort_t*)(ws + 48 * MB);
    ushort_t* Yb   = (ushort_t*)(ws + 48 * MB);
    ushort_t* KP   = (ushort_t*)(ws + 56 * MB);   // also XP, then H_b
    ushort_t* Hb   = (ushort_t*)(ws + 56 * MB);
    float*    ctxb = (float*)(ws + 93847552ull);            // 89.5 MB
    ushort_t* ctxTb = (ushort_t*)(ws + 93847552ull + MB);   // 90.5 MB
    char* smalls = ws + 91 * MB + 393216ull;                // 91.375 MB
    float*    diagK  = (float*)(smalls);                    // 256 KB
    float*    ksum   = (float*)(smalls + 262144);           // 16 KB
    float*    denomB = (float*)(smalls + 278528);           // 256 KB
    unsigned* kmax16 = (unsigned*)(smalls + 540672);        // 64 B
    ushort_t* projBF = (ushort_t*)(smalls + 541184);        // 32 KB
    ushort_t* OUTb = (ushort_t*)(ws + 92 * MB);
    ushort_t* WqBF = (ushort_t*)(ws + 100 * MB);
    ushort_t* WkBF = (ushort_t*)(ws + 102 * MB);
    ushort_t* WvBF = (ushort_t*)(ws + 104 * MB);
    ushort_t* WoBF = (ushort_t*)(ws + 106 * MB);
    ushort_t* W1BF = (ushort_t*)(ws + 108 * MB);
    ushort_t* W2BF = (ushort_t*)(ws + 116 * MB);
    float* Qbuf = (float*)d_out;

    dim3 blk(256);

    // one-time fp32 -> bf16 conversions
    cvt_bf16<<<dim3(ROWS * DMODEL / 1024), blk, 0, stream>>>(video, videoBF, ROWS * DMODEL / 4);
    cvt_bf16<<<dim3(DMODEL * DMODEL / 1024), blk, 0, stream>>>(Wq, WqBF, DMODEL * DMODEL / 4);
    cvt_bf16<<<dim3(DMODEL * DMODEL / 1024), blk, 0, stream>>>(Wk, WkBF, DMODEL * DMODEL / 4);
    cvt_bf16<<<dim3(DMODEL * DMODEL / 1024), blk, 0, stream>>>(Wv, WvBF, DMODEL * DMODEL / 4);
    cvt_bf16<<<dim3(DMODEL * DMODEL / 1024), blk, 0, stream>>>(Wo, WoBF, DMODEL * DMODEL / 4);
    cvt_bf16<<<dim3(DFF * DMODEL / 1024), blk, 0, stream>>>(W1, W1BF, DFF * DMODEL / 4);
    cvt_bf16<<<dim3(DFF * DMODEL / 1024), blk, 0, stream>>>(W2, W2BF, DFF * DMODEL / 4);
    cvt_bf16<<<dim3(16), blk, 0, stream>>>(proj, projBF, MFEAT * DH / 4);

    // Q projection, all rows (fp32 out into d_out)
    gemm_mfma<4, float><<<dim3(8, ROWS / 128), blk, 0, stream>>>(
        videoBF, WqBF, bq, Qbuf, DMODEL, DMODEL, 0);

    dim3 gP(8, 32);   // per-batch 4096-row projection grid

    for (int b = 0; b < BATCH; ++b) {
        const size_t roff = (size_t)b * N_TOK;
        const ushort_t* vbf = videoBF + roff * DMODEL;
        float* Qb = Qbuf + roff * DMODEL;

        // K/V projections (per batch)
        gemm_mfma<4, ushort_t><<<gP, blk, 0, stream>>>(vbf, WkBF, bk, Kb, DMODEL, DMODEL, 0);
        gemm_mfma<4, ushort_t><<<gP, blk, 0, stream>>>(vbf, WvBF, bv, Vb, DMODEL, DMODEL, 0);
        vt_kernel<<<dim3(64, 16), blk, 0, stream>>>(Vb, VTb);
        diagk_kernel<<<dim3(1024), blk, 0, stream>>>(Kb, diagK);

        hipMemsetAsync(ctxb, 0, MB, stream);
        hipMemsetAsync(kmax16, 0, 64, stream);

        // K-side features: max pass, then exp pass -> KP[h][m][n]
        xk_kernel<<<dim3(2, 32, 16), blk, 0, stream>>>(projBF, Kb, diagK, kmax16, KP, 0);
        xk_kernel<<<dim3(2, 32, 16), blk, 0, stream>>>(projBF, Kb, diagK, kmax16, KP, 1);
        ksum_kernel<<<dim3(1024), blk, 0, stream>>>(KP, ksum);
        ctx_mfma<<<dim3(8, 2, 16), blk, 0, stream>>>(KP, VTb, ctxb);
        ctx_transpose<<<dim3(16), blk, 0, stream>>>(ctxb, ctxTb);

        // Q-side (XP reuses the KP region)
        xp_gemm<<<dim3(2, 32, 16), blk, 0, stream>>>(Qb, projBF, KP);
        qp_kernel<<<dim3(2048), blk, 0, stream>>>(KP, Qb, ksum, denomB);
        out_gemm<<<dim3(32, 16), blk, 0, stream>>>(KP, ctxTb, denomB, OUTb);

        // Wo, LN1, FFN, LN2 (all per batch)
        gemm_mfma<4, ushort_t><<<gP, blk, 0, stream>>>(OUTb, WoBF, bo, Yb, DMODEL, DMODEL, 0);
        ln_kernel<<<dim3(N_TOK), blk, 0, stream>>>(
            video + roff * DMODEL, Yb, 1, g2, be2, Qb, XBFb);
        gemm_mfma<4, ushort_t><<<dim3(32, 32), blk, 0, stream>>>(
            XBFb, W1BF, b1, Hb, DFF, DMODEL, 1);
        gemm_mfma<2, ushort_t><<<dim3(16, 32), blk, 0, stream>>>(
            Hb, W2BF, b2, Fb, DMODEL, DFF, 0);
        ln_kernel<<<dim3(N_TOK), blk, 0, stream>>>(
            Qb, Fb, 1, g3, be3, Qb, nullptr);
    }
}

// Round 2
// 1657.813 us; speedup vs baseline: 1.1075x; 1.0618x over previous
//
#include <hip/hip_runtime.h>
#include <hip/hip_bf16.h>

// PerformerSelfLayer: B=4, N=4096, D=1024, H=16, DH=64, M=256, DFF=4096
#define N_TOK   4096
#define DMODEL  1024
#define NHEADS  16
#define DH      64
#define MFEAT   256
#define DFF     4096
#define BATCH   4
#define ROWS    (BATCH * N_TOK)   // 16384

#define NORMF      0.35355339059327373f  // 64^-0.25
#define HALF_NORM2 0.0625f               // 0.5 * norm^2
#define RATIO      0.0625f               // 256^-0.5
#define EPSK       1e-4f
#define LNEPS      1e-5f

typedef unsigned short ushort_t;
using bfrag = __attribute__((ext_vector_type(8))) short;   // 8 bf16 (4 VGPRs)
using facc  = __attribute__((ext_vector_type(4))) float;   // 4 fp32 acc
using ush8  = __attribute__((ext_vector_type(8))) unsigned short;

__device__ __forceinline__ float b2f(ushort_t u) {
    return __bfloat162float(__builtin_bit_cast(__hip_bfloat16, u));
}
__device__ __forceinline__ ushort_t f2b(float f) {
    return __builtin_bit_cast(ushort_t, __float2bfloat16(f));
}
__device__ __forceinline__ void stC(float* p, float v) { *p = v; }
__device__ __forceinline__ void stC(ushort_t* p, float v) { *p = f2b(v); }

// async global->LDS DMA, 16B per lane. LDS dest must be wave-uniform base + lane*16.
__device__ __forceinline__ void gload_lds16(const void* g, void* l) {
    __builtin_amdgcn_global_load_lds(
        (const __attribute__((address_space(1))) unsigned int*)g,
        (__attribute__((address_space(3))) unsigned int*)l, 16, 0, 0);
}

// order-preserving float->uint key for atomicMax; memset(0) is below any real key
__device__ __forceinline__ unsigned fkey(float f) {
    unsigned u = __float_as_uint(f);
    return (u & 0x80000000u) ? ~u : (u | 0x80000000u);
}
__device__ __forceinline__ float fdec(unsigned k) {
    return (k & 0x80000000u) ? __uint_as_float(k ^ 0x80000000u) : __uint_as_float(~k);
}

// ---------------- fp32 -> bf16 conversion (vectorized)
__global__ __launch_bounds__(256) void cvt_bf16(const float* __restrict__ s,
                                                ushort_t* __restrict__ d, int n4) {
    int i = blockIdx.x * 256 + threadIdx.x;
    if (i >= n4) return;
    float4 v = ((const float4*)s)[i];
    ((ushort4*)d)[i] = make_ushort4(f2b(v.x), f2b(v.y), f2b(v.z), f2b(v.w));
}

// ---------------- bf16 MFMA GEMM: C[M,N] = A[M,K] (bf16) * W[N,K]^T (bf16) + bias
// 2-phase dbuf: stage(next) -> compute(cur) -> one barrier per K-step (T3 minimum)
template <int FJ, typename OT>
__global__ __launch_bounds__(256) void gemm_mfma(
    const ushort_t* __restrict__ A, const ushort_t* __restrict__ W,
    const float* __restrict__ bias, OT* __restrict__ C,
    int Nout, int K, int relu)
{
    constexpr int BN = FJ * 32;
    __shared__ short As[2][128 * 32];
    __shared__ short Ws[2][BN * 32];
    const int t = threadIdx.x;
    // XCD swizzle: all grids here have nwg % 8 == 0; bijective chunked remap
    const unsigned nwg = gridDim.x * gridDim.y;
    const unsigned flat = blockIdx.y * gridDim.x + blockIdx.x;
    const unsigned cpx = nwg >> 3;
    const unsigned wg = (flat & 7) * cpx + (flat >> 3);
    const int m0 = (int)(wg / gridDim.x) * 128, n0 = (int)(wg % gridDim.x) * BN;
    const int lane = t & 63, wave = t >> 6;
    const int wr = (wave >> 1) * 64, wc = (wave & 1) * (FJ * 16);
    const int lm = lane & 15, kq = (lane >> 4) * 8;
    facc acc[4][FJ];
#pragma unroll
    for (int i = 0; i < 4; ++i)
#pragma unroll
        for (int j = 0; j < FJ; ++j) acc[i][j] = (facc){0.f, 0.f, 0.f, 0.f};

    auto stage = [&](int b, int k0) {
#pragma unroll
        for (int it = 0; it < 2; ++it) {
            int ch = t + it * 256;
            gload_lds16(A + (size_t)(m0 + (ch >> 2)) * K + k0 + (ch & 3) * 8, &As[b][ch * 8]);
        }
#pragma unroll
        for (int it = 0; it < BN / 64; ++it) {
            int ch = t + it * 256;
            gload_lds16(W + (size_t)(n0 + (ch >> 2)) * K + k0 + (ch & 3) * 8, &Ws[b][ch * 8]);
        }
    };

    stage(0, 0);
    __syncthreads();
    int buf = 0;
    for (int k0 = 0; k0 < K; k0 += 32) {
        if (k0 + 32 < K) stage(buf ^ 1, k0 + 32);
        bfrag af[4], bf[FJ];
#pragma unroll
        for (int i = 0; i < 4; ++i) af[i] = *(bfrag*)&As[buf][(wr + i * 16 + lm) * 32 + kq];
#pragma unroll
        for (int j = 0; j < FJ; ++j) bf[j] = *(bfrag*)&Ws[buf][(wc + j * 16 + lm) * 32 + kq];
#pragma unroll
        for (int i = 0; i < 4; ++i)
#pragma unroll
            for (int j = 0; j < FJ; ++j)
                acc[i][j] = __builtin_amdgcn_mfma_f32_16x16x32_bf16(af[i], bf[j], acc[i][j], 0, 0, 0);
        __syncthreads();
        buf ^= 1;
    }
    const int rq = (lane >> 4) * 4;
#pragma unroll
    for (int i = 0; i < 4; ++i)
#pragma unroll
        for (int j = 0; j < FJ; ++j) {
            int col = n0 + wc + j * 16 + lm;
            float bc = bias[col];
#pragma unroll
            for (int r = 0; r < 4; ++r) {
                int row = m0 + wr + i * 16 + rq + r;
                float v = acc[i][j][r] + bc;
                if (relu) v = fmaxf(v, 0.f);
                stC(C + (size_t)row * Nout + col, v);
            }
        }
}

// ---------------- fused K+V projection: one launch, 512 blocks (2/CU)
// grid (16,32): col-tiles 0-7 -> K via Wk, 8-15 -> V via Wv. M=N=K=1024 per batch.
__global__ __launch_bounds__(256) void gemm_kv(
    const ushort_t* __restrict__ A,
    const ushort_t* __restrict__ WK, const ushort_t* __restrict__ WV,
    const float* __restrict__ bK, const float* __restrict__ bV,
    ushort_t* __restrict__ CK, ushort_t* __restrict__ CV)
{
    __shared__ short As[2][128 * 32];
    __shared__ short Ws[2][128 * 32];
    const int t = threadIdx.x;
    const unsigned nwg = gridDim.x * gridDim.y;      // 512
    const unsigned flat = blockIdx.y * gridDim.x + blockIdx.x;
    const unsigned cpx = nwg >> 3;
    const unsigned wg = (flat & 7) * cpx + (flat >> 3);
    const int m0 = (int)(wg / gridDim.x) * 128;
    const int nt = (int)(wg % gridDim.x);            // 0..15
    const ushort_t* W = (nt < 8) ? WK : WV;
    const float* bias = (nt < 8) ? bK : bV;
    ushort_t* C = (nt < 8) ? CK : CV;
    const int n0 = (nt & 7) * 128;
    const int lane = t & 63, wave = t >> 6;
    const int wr = (wave >> 1) * 64, wc = (wave & 1) * 64;
    const int lm = lane & 15, kq = (lane >> 4) * 8;
    facc acc[4][4];
#pragma unroll
    for (int i = 0; i < 4; ++i)
#pragma unroll
        for (int j = 0; j < 4; ++j) acc[i][j] = (facc){0.f, 0.f, 0.f, 0.f};

    auto stage = [&](int b, int k0) {
#pragma unroll
        for (int it = 0; it < 2; ++it) {
            int ch = t + it * 256;
            gload_lds16(A + (size_t)(m0 + (ch >> 2)) * DMODEL + k0 + (ch & 3) * 8, &As[b][ch * 8]);
            gload_lds16(W + (size_t)(n0 + (ch >> 2)) * DMODEL + k0 + (ch & 3) * 8, &Ws[b][ch * 8]);
        }
    };

    stage(0, 0);
    __syncthreads();
    int buf = 0;
    for (int k0 = 0; k0 < DMODEL; k0 += 32) {
        if (k0 + 32 < DMODEL) stage(buf ^ 1, k0 + 32);
        bfrag af[4], bf[4];
#pragma unroll
        for (int i = 0; i < 4; ++i) af[i] = *(bfrag*)&As[buf][(wr + i * 16 + lm) * 32 + kq];
#pragma unroll
        for (int j = 0; j < 4; ++j) bf[j] = *(bfrag*)&Ws[buf][(wc + j * 16 + lm) * 32 + kq];
#pragma unroll
        for (int i = 0; i < 4; ++i)
#pragma unroll
            for (int j = 0; j < 4; ++j)
                acc[i][j] = __builtin_amdgcn_mfma_f32_16x16x32_bf16(af[i], bf[j], acc[i][j], 0, 0, 0);
        __syncthreads();
        buf ^= 1;
    }
    const int rq = (lane >> 4) * 4;
#pragma unroll
    for (int i = 0; i < 4; ++i)
#pragma unroll
        for (int j = 0; j < 4; ++j) {
            int col = n0 + wc + j * 16 + lm;
            float bc = bias[col];
#pragma unroll
            for (int r = 0; r < 4; ++r) {
                int row = m0 + wr + i * 16 + rq + r;
                C[(size_t)row * DMODEL + col] = f2b(acc[i][j][r] + bc);
            }
        }
}

// ---------------- V_b [4096][1024] -> VT [16][64][4096] (per-head transpose)
__global__ __launch_bounds__(256) void vt_kernel(
    const ushort_t* __restrict__ V, ushort_t* __restrict__ VT)
{
    __shared__ ushort_t tile[64][68];
    const int t = threadIdx.x;
    const int n0 = blockIdx.x * 64, h = blockIdx.y;
#pragma unroll
    for (int i = 0; i < 4; ++i) {
        int idx = t + i * 256;                    // 1024 ushort4 chunks
        int nl = idx >> 4, d4 = (idx & 15) * 4;
        ushort4 v = *(const ushort4*)(V + (size_t)(n0 + nl) * DMODEL + h * DH + d4);
        tile[nl][d4 + 0] = v.x; tile[nl][d4 + 1] = v.y;
        tile[nl][d4 + 2] = v.z; tile[nl][d4 + 3] = v.w;
    }
    __syncthreads();
#pragma unroll
    for (int i = 0; i < 4; ++i) {
        int idx = t + i * 256;
        int d = idx >> 4, n4 = (idx & 15) * 4;
        ushort4 o = make_ushort4(tile[n4][d], tile[n4 + 1][d], tile[n4 + 2][d], tile[n4 + 3][d]);
        *(ushort4*)(VT + (size_t)h * DH * N_TOK + (size_t)d * N_TOK + n0 + n4) = o;
    }
}

// ---------------- diagK[h][n] = sum_dh K[n][h*64+dh]^2  (wave per n, shuffle)
__global__ __launch_bounds__(256) void diagk_kernel(
    const ushort_t* __restrict__ Kb, float* __restrict__ diagK)
{
    const int lane = threadIdx.x & 63, wave = threadIdx.x >> 6;
    const int n = blockIdx.x * 4 + wave;
    const ushort_t* kr = Kb + (size_t)n * DMODEL + lane * 16;
    ush8 a = *(const ush8*)kr;
    ush8 b = *(const ush8*)(kr + 8);
    float s = 0.f;
#pragma unroll
    for (int e = 0; e < 8; ++e) { float x = b2f(a[e]); s += x * x; }
#pragma unroll
    for (int e = 0; e < 8; ++e) { float x = b2f(b[e]); s += x * x; }
    s += __shfl_xor(s, 1);
    s += __shfl_xor(s, 2);
    if ((lane & 3) == 0) diagK[(size_t)(lane >> 2) * N_TOK + n] = s;
}

// ---------------- K-side feature GEMM: acc = proj[m,:] . K[n, h*64:] (K=64, MFMA, dbuf)
// mode 0: per-h global max -> atomicMax kmax16.  mode 1: exp epilogue -> KP[h][m][n] bf16
__global__ __launch_bounds__(256) void xk_kernel(
    const ushort_t* __restrict__ projBF,   // [256][64]
    const ushort_t* __restrict__ Kb,       // [4096][1024]
    const float* __restrict__ diagK,       // [16][4096]
    unsigned* __restrict__ kmax16,         // [16]
    ushort_t* __restrict__ KP,             // [16][256][4096]
    int mode)
{
    __shared__ short As[2][128 * 32];
    __shared__ short Ws[2][128 * 32];
    const int t = threadIdx.x;
    const int m0 = blockIdx.x * 128, n0 = blockIdx.y * 128, h = blockIdx.z;
    const ushort_t* Kh = Kb + h * DH;
    const int lane = t & 63, wave = t >> 6;
    const int wr = (wave >> 1) * 64, wc = (wave & 1) * 64;
    const int lm = lane & 15, kq = (lane >> 4) * 8;
    facc acc[4][4];
#pragma unroll
    for (int i = 0; i < 4; ++i)
#pragma unroll
        for (int j = 0; j < 4; ++j) acc[i][j] = (facc){0.f, 0.f, 0.f, 0.f};

    auto stage = [&](int b, int k0) {
#pragma unroll
        for (int it = 0; it < 2; ++it) {
            int ch = t + it * 256;
            gload_lds16(projBF + (size_t)(m0 + (ch >> 2)) * DH + k0 + (ch & 3) * 8, &As[b][ch * 8]);
            gload_lds16(Kh + (size_t)(n0 + (ch >> 2)) * DMODEL + k0 + (ch & 3) * 8, &Ws[b][ch * 8]);
        }
    };

    stage(0, 0);
    __syncthreads();
    int buf = 0;
    for (int k0 = 0; k0 < DH; k0 += 32) {
        if (k0 + 32 < DH) stage(buf ^ 1, k0 + 32);
        bfrag af[4], bf[4];
#pragma unroll
        for (int i = 0; i < 4; ++i) af[i] = *(bfrag*)&As[buf][(wr + i * 16 + lm) * 32 + kq];
#pragma unroll
        for (int j = 0; j < 4; ++j) bf[j] = *(bfrag*)&Ws[buf][(wc + j * 16 + lm) * 32 + kq];
#pragma unroll
        for (int i = 0; i < 4; ++i)
#pragma unroll
            for (int j = 0; j < 4; ++j)
                acc[i][j] = __builtin_amdgcn_mfma_f32_16x16x32_bf16(af[i], bf[j], acc[i][j], 0, 0, 0);
        __syncthreads();
        buf ^= 1;
    }
    const int rq = (lane >> 4) * 4;
    if (mode == 0) {
        float mx = -1e30f;
#pragma unroll
        for (int i = 0; i < 4; ++i)
#pragma unroll
            for (int j = 0; j < 4; ++j)
#pragma unroll
                for (int r = 0; r < 4; ++r) mx = fmaxf(mx, acc[i][j][r]);
        mx *= NORMF;
#pragma unroll
        for (int o = 32; o >= 1; o >>= 1) mx = fmaxf(mx, __shfl_xor(mx, o));
        if (lane == 0) atomicMax(kmax16 + h, fkey(mx));
    } else {
        const float stab = fdec(kmax16[h]);
        ushort_t* kb = KP + (size_t)h * MFEAT * N_TOK;
#pragma unroll
        for (int j = 0; j < 4; ++j) {
            int n = n0 + wc + j * 16 + lm;
            float dg = HALF_NORM2 * diagK[(size_t)h * N_TOK + n] + stab;
#pragma unroll
            for (int i = 0; i < 4; ++i)
#pragma unroll
                for (int r = 0; r < 4; ++r) {
                    int m = m0 + wr + i * 16 + rq + r;
                    float x = NORMF * acc[i][j][r];
                    kb[(size_t)m * N_TOK + n] = f2b(RATIO * (expf(x - dg) + EPSK));
                }
        }
    }
}

// ---------------- ksum[h*256+m] = sum_n KP[h][m][n]  (wave per row)
__global__ __launch_bounds__(256) void ksum_kernel(
    const ushort_t* __restrict__ KP, float* __restrict__ ksum)
{
    const int lane = threadIdx.x & 63, wave = threadIdx.x >> 6;
    const int row = blockIdx.x * 4 + wave;
    const ushort_t* kr = KP + (size_t)row * N_TOK;
    float s = 0.f;
#pragma unroll
    for (int it = 0; it < 8; ++it) {
        ush8 v = *(const ush8*)(kr + it * 512 + lane * 8);
#pragma unroll
        for (int e = 0; e < 8; ++e) s += b2f(v[e]);
    }
#pragma unroll
    for (int o = 32; o >= 1; o >>= 1) s += __shfl_xor(s, o);
    if (lane == 0) ksum[row] = s;
}

// ---------------- ctxp[z][h][m][d] = sum_{n in z-chunk} KP[h][m][n] * VT[h][d][n]
// dbuf MFMA, plain stores into per-z partials (no atomics)
__global__ __launch_bounds__(256) void ctx_mfma(
    const ushort_t* __restrict__ KP, const ushort_t* __restrict__ VT,
    float* __restrict__ ctxp)
{
    __shared__ short As[2][128 * 32];
    __shared__ short Vs[2][64 * 32];
    const int t = threadIdx.x;
    const int z = blockIdx.x, mh = blockIdx.y, h = blockIdx.z;
    const ushort_t* A = KP + (size_t)h * MFEAT * N_TOK + (size_t)mh * 128 * N_TOK;
    const ushort_t* W = VT + (size_t)h * DH * N_TOK;
    const int lane = t & 63, wave = t >> 6;
    const int wr = (wave >> 1) * 64, wc = (wave & 1) * 32;
    const int lm = lane & 15, kq = (lane >> 4) * 8;
    facc acc[4][2];
#pragma unroll
    for (int i = 0; i < 4; ++i)
#pragma unroll
        for (int j = 0; j < 2; ++j) acc[i][j] = (facc){0.f, 0.f, 0.f, 0.f};

    auto stage = [&](int b, int k0) {
#pragma unroll
        for (int it = 0; it < 2; ++it) {
            int ch = t + it * 256;
            gload_lds16(A + (size_t)(ch >> 2) * N_TOK + k0 + (ch & 3) * 8, &As[b][ch * 8]);
        }
        gload_lds16(W + (size_t)(t >> 2) * N_TOK + k0 + (t & 3) * 8, &Vs[b][t * 8]);
    };

    const int kbeg = z * 512, kend = kbeg + 512;
    stage(0, kbeg);
    __syncthreads();
    int buf = 0;
    for (int k0 = kbeg; k0 < kend; k0 += 32) {
        if (k0 + 32 < kend) stage(buf ^ 1, k0 + 32);
        bfrag af[4], bf[2];
#pragma unroll
        for (int i = 0; i < 4; ++i) af[i] = *(bfrag*)&As[buf][(wr + i * 16 + lm) * 32 + kq];
#pragma unroll
        for (int j = 0; j < 2; ++j) bf[j] = *(bfrag*)&Vs[buf][(wc + j * 16 + lm) * 32 + kq];
#pragma unroll
        for (int i = 0; i < 4; ++i)
#pragma unroll
            for (int j = 0; j < 2; ++j)
                acc[i][j] = __builtin_amdgcn_mfma_f32_16x16x32_bf16(af[i], bf[j], acc[i][j], 0, 0, 0);
        __syncthreads();
        buf ^= 1;
    }
    const int rq = (lane >> 4) * 4;
    float* cb = ctxp + ((size_t)(z * NHEADS + h) * MFEAT + mh * 128) * DH;
#pragma unroll
    for (int i = 0; i < 4; ++i)
#pragma unroll
        for (int j = 0; j < 2; ++j)
#pragma unroll
            for (int r = 0; r < 4; ++r) {
                int m = wr + i * 16 + rq + r;
                int d = wc + j * 16 + lm;
                cb[(size_t)m * DH + d] = acc[i][j][r];
            }
}

// ---------------- sum 8 z-partials + transpose: ctxT[h][64][256] bf16
// grid 64: blockIdx.x = h*4 + mb (64-row chunk of m)
__global__ __launch_bounds__(256) void ctx_transpose(
    const float* __restrict__ ctxp, ushort_t* __restrict__ ctxT)
{
    __shared__ float tile[64][65];
    const int h = blockIdx.x >> 2, mb = blockIdx.x & 3, t = threadIdx.x;
#pragma unroll
    for (int i = 0; i < 16; ++i) {
        int idx = t + i * 256;
        int ml = idx >> 6, d = idx & 63;
        int m = mb * 64 + ml;
        float s = 0.f;
#pragma unroll
        for (int z = 0; z < 8; ++z)
            s += ctxp[((size_t)(z * NHEADS + h) * MFEAT + m) * DH + d];
        tile[ml][d] = s;
    }
    __syncthreads();
    ushort_t* ob = ctxT + (size_t)h * DH * MFEAT;
#pragma unroll
    for (int i = 0; i < 16; ++i) {
        int idx = t + i * 256;
        int d = idx >> 6, ml = idx & 63;
        ob[(size_t)d * MFEAT + mb * 64 + ml] = f2b(tile[ml][d]);
    }
}

// ---------------- XP[h][n][m] = NORMF * (Q[n,h*64:] . proj[m,:]) — MFMA, K=64
__global__ __launch_bounds__(256) void xp_gemm(
    const float* __restrict__ Q, const ushort_t* __restrict__ projBF,
    ushort_t* __restrict__ XP)
{
    __shared__ short As[128][40];
    __shared__ short Ws[128][40];
    const int t = threadIdx.x;
    const int m0 = blockIdx.x * 128, n0v = blockIdx.y * 128, h = blockIdx.z;
    const float* Qb = Q + h * DH;
    const int lane = t & 63, wave = t >> 6;
    const int wr = (wave >> 1) * 64, wc = (wave & 1) * 64;
    const int lm = lane & 15, kq = (lane >> 4) * 8;
    facc acc[4][4];
#pragma unroll
    for (int i = 0; i < 4; ++i)
#pragma unroll
        for (int j = 0; j < 4; ++j) acc[i][j] = (facc){0.f, 0.f, 0.f, 0.f};

    for (int k0 = 0; k0 < 64; k0 += 32) {
#pragma unroll
        for (int it = 0; it < 4; ++it) {
            int ch = t + it * 256;
            int row = ch >> 3, c4 = (ch & 7) * 4;
            float4 v = *(const float4*)(Qb + (size_t)(n0v + row) * DMODEL + k0 + c4);
            As[row][c4 + 0] = (short)f2b(v.x);
            As[row][c4 + 1] = (short)f2b(v.y);
            As[row][c4 + 2] = (short)f2b(v.z);
            As[row][c4 + 3] = (short)f2b(v.w);
        }
#pragma unroll
        for (int it = 0; it < 2; ++it) {
            int ch = t + it * 256;
            int row = ch >> 2, c8 = (ch & 3) * 8;
            *(uint4*)&Ws[row][c8] = *(const uint4*)(projBF + (size_t)(m0 + row) * DH + k0 + c8);
        }
        __syncthreads();
        bfrag af[4], bf[4];
#pragma unroll
        for (int i = 0; i < 4; ++i) af[i] = *(bfrag*)&As[wr + i * 16 + lm][kq];
#pragma unroll
        for (int j = 0; j < 4; ++j) bf[j] = *(bfrag*)&Ws[wc + j * 16 + lm][kq];
#pragma unroll
        for (int i = 0; i < 4; ++i)
#pragma unroll
            for (int j = 0; j < 4; ++j)
                acc[i][j] = __builtin_amdgcn_mfma_f32_16x16x32_bf16(af[i], bf[j], acc[i][j], 0, 0, 0);
        __syncthreads();
    }
    const int rq = (lane >> 4) * 4;
    ushort_t* xb = XP + (size_t)h * N_TOK * MFEAT;
#pragma unroll
    for (int i = 0; i < 4; ++i)
#pragma unroll
        for (int j = 0; j < 4; ++j) {
            int col = m0 + wc + j * 16 + lm;
#pragma unroll
            for (int r = 0; r < 4; ++r) {
                int row = n0v + wr + i * 16 + rq + r;
                xb[(size_t)row * MFEAT + col] = f2b(NORMF * acc[i][j][r]);
            }
        }
}

// ---------------- per-row q-features: stab/exp -> QP bf16 in-place + denom
__global__ __launch_bounds__(256) void qp_kernel(
    ushort_t* __restrict__ XP, const float* __restrict__ Q,
    const float* __restrict__ ksum, float* __restrict__ denom)
{
    const int lane = threadIdx.x & 63, wave = threadIdx.x >> 6;
    const int row0 = (blockIdx.x * 4 + wave) * 8;
    for (int rr = 0; rr < 8; ++rr) {
        const int row = row0 + rr;
        const int h = row >> 12, n = row & 4095;
        ushort_t* xr = XP + (size_t)row * MFEAT + lane * 4;
        ushort4 xv = *(ushort4*)xr;
        float x0 = b2f(xv.x), x1 = b2f(xv.y), x2 = b2f(xv.z), x3 = b2f(xv.w);
        float qv = Q[(size_t)n * DMODEL + h * DH + lane];
        float ss = qv * qv;
#pragma unroll
        for (int o = 32; o >= 1; o >>= 1) ss += __shfl_xor(ss, o);
        float mx = fmaxf(fmaxf(x0, x1), fmaxf(x2, x3));
#pragma unroll
        for (int o = 32; o >= 1; o >>= 1) mx = fmaxf(mx, __shfl_xor(mx, o));
        const float sh = HALF_NORM2 * ss + mx;
        float p0 = RATIO * (expf(x0 - sh) + EPSK);
        float p1 = RATIO * (expf(x1 - sh) + EPSK);
        float p2 = RATIO * (expf(x2 - sh) + EPSK);
        float p3 = RATIO * (expf(x3 - sh) + EPSK);
        ushort4 pv = make_ushort4(f2b(p0), f2b(p1), f2b(p2), f2b(p3));
        *(ushort4*)xr = pv;
        float4 ks4 = *(const float4*)(ksum + h * MFEAT + lane * 4);
        float dn = b2f(pv.x) * ks4.x + b2f(pv.y) * ks4.y + b2f(pv.z) * ks4.z + b2f(pv.w) * ks4.w;
#pragma unroll
        for (int o = 32; o >= 1; o >>= 1) dn += __shfl_xor(dn, o);
        if (lane == 0) denom[row] = dn;
    }
}

// ---------------- OUT[n][h*64+d] = (QP . ctxT[d]) / denom — MFMA, K=256, dbuf
__global__ __launch_bounds__(256) void out_gemm(
    const ushort_t* __restrict__ XP, const ushort_t* __restrict__ ctxT,
    const float* __restrict__ denom, ushort_t* __restrict__ OUT)
{
    __shared__ short As[2][128 * 32];
    __shared__ short Ws[2][64 * 32];
    const int t = threadIdx.x;
    const int n0 = blockIdx.x * 128, h = blockIdx.y;
    const ushort_t* A = XP + (size_t)h * N_TOK * MFEAT;
    const ushort_t* W = ctxT + (size_t)h * DH * MFEAT;
    const float* dnb = denom + (size_t)h * N_TOK;
    ushort_t* ob = OUT + h * DH;
    const int lane = t & 63, wave = t >> 6;
    const int wr = (wave >> 1) * 64, wc = (wave & 1) * 32;
    const int lm = lane & 15, kq = (lane >> 4) * 8;
    facc acc[4][2];
#pragma unroll
    for (int i = 0; i < 4; ++i)
#pragma unroll
        for (int j = 0; j < 2; ++j) acc[i][j] = (facc){0.f, 0.f, 0.f, 0.f};

    auto stage = [&](int b, int k0) {
#pragma unroll
        for (int it = 0; it < 2; ++it) {
            int ch = t + it * 256;
            gload_lds16(A + (size_t)(n0 + (ch >> 2)) * MFEAT + k0 + (ch & 3) * 8, &As[b][ch * 8]);
        }
        gload_lds16(W + (size_t)(t >> 2) * MFEAT + k0 + (t & 3) * 8, &Ws[b][t * 8]);
    };

    stage(0, 0);
    __syncthreads();
    int buf = 0;
    for (int k0 = 0; k0 < MFEAT; k0 += 32) {
        if (k0 + 32 < MFEAT) stage(buf ^ 1, k0 + 32);
        bfrag af[4], bf[2];
#pragma unroll
        for (int i = 0; i < 4; ++i) af[i] = *(bfrag*)&As[buf][(wr + i * 16 + lm) * 32 + kq];
#pragma unroll
        for (int j = 0; j < 2; ++j) bf[j] = *(bfrag*)&Ws[buf][(wc + j * 16 + lm) * 32 + kq];
#pragma unroll
        for (int i = 0; i < 4; ++i)
#pragma unroll
            for (int j = 0; j < 2; ++j)
                acc[i][j] = __builtin_amdgcn_mfma_f32_16x16x32_bf16(af[i], bf[j], acc[i][j], 0, 0, 0);
        __syncthreads();
        buf ^= 1;
    }
    const int rq = (lane >> 4) * 4;
#pragma unroll
    for (int i = 0; i < 4; ++i)
#pragma unroll
        for (int r = 0; r < 4; ++r) {
            int row = n0 + wr + i * 16 + rq + r;
            float inv = 1.f / dnb[row];
#pragma unroll
            for (int j = 0; j < 2; ++j) {
                int col = wc + j * 16 + lm;
                ob[(size_t)row * DMODEL + col] = f2b(acc[i][j][r] * inv);
            }
        }
}

// ---------------- LayerNorm: out = LN(A + Badd)*g + b; optional bf16 copy
// float4-vectorized, wave-shuffle reduce + 4-wave LDS combine (2 barriers)
__global__ __launch_bounds__(256) void ln_kernel(
    const float* __restrict__ A, const void* __restrict__ Badd, int badd_bf16,
    const float* __restrict__ g, const float* __restrict__ bb,
    float* __restrict__ out, ushort_t* __restrict__ out_bf)
{
    __shared__ float red[8];
    const int row = blockIdx.x, t = threadIdx.x;
    const int lane = t & 63, wave = t >> 6;
    float4 av = ((const float4*)(A + (size_t)row * DMODEL))[t];
    float a0, a1, a2, a3;
    if (badd_bf16) {
        ushort4 bv4 = ((const ushort4*)Badd)[(size_t)row * (DMODEL / 4) + t];
        a0 = b2f(bv4.x); a1 = b2f(bv4.y); a2 = b2f(bv4.z); a3 = b2f(bv4.w);
    } else {
        float4 bf4 = ((const float4*)Badd)[(size_t)row * (DMODEL / 4) + t];
        a0 = bf4.x; a1 = bf4.y; a2 = bf4.z; a3 = bf4.w;
    }
    float v0 = av.x + a0, v1 = av.y + a1, v2 = av.z + a2, v3 = av.w + a3;
    float s = v0 + v1 + v2 + v3;
#pragma unroll
    for (int o = 32; o >= 1; o >>= 1) s += __shfl_xor(s, o);
    if (lane == 0) red[wave] = s;
    __syncthreads();
    float mu = (red[0] + red[1] + red[2] + red[3]) * (1.f / DMODEL);
    float d0 = v0 - mu, d1 = v1 - mu, d2 = v2 - mu, d3 = v3 - mu;
    float sq = d0 * d0 + d1 * d1 + d2 * d2 + d3 * d3;
#pragma unroll
    for (int o = 32; o >= 1; o >>= 1) sq += __shfl_xor(sq, o);
    if (lane == 0) red[4 + wave] = sq;
    __syncthreads();
    float rstd = rsqrtf((red[4] + red[5] + red[6] + red[7]) * (1.f / DMODEL) + LNEPS);
    float4 gv = ((const float4*)g)[t];
    float4 bv = ((const float4*)bb)[t];
    float o0 = d0 * rstd * gv.x + bv.x;
    float o1 = d1 * rstd * gv.y + bv.y;
    float o2 = d2 * rstd * gv.z + bv.z;
    float o3 = d3 * rstd * gv.w + bv.w;
    ((float4*)(out + (size_t)row * DMODEL))[t] = make_float4(o0, o1, o2, o3);
    if (out_bf)
        ((ushort4*)(out_bf + (size_t)row * DMODEL))[t] =
            make_ushort4(f2b(o0), f2b(o1), f2b(o2), f2b(o3));
}

extern "C" void kernel_launch(void* const* d_in, const int* in_sizes, int n_in,
                              void* d_out, int out_size, void* d_ws, size_t ws_size,
                              hipStream_t stream)
{
    const float* video = (const float*)d_in[0];
    const float* Wq = (const float*)d_in[1];
    const float* bq = (const float*)d_in[2];
    const float* Wk = (const float*)d_in[3];
    const float* bk = (const float*)d_in[4];
    const float* Wv = (const float*)d_in[5];
    const float* bv = (const float*)d_in[6];
    const float* Wo = (const float*)d_in[7];
    const float* bo = (const float*)d_in[8];
    const float* proj = (const float*)d_in[9];
    const float* W1 = (const float*)d_in[10];
    const float* b1 = (const float*)d_in[11];
    const float* W2 = (const float*)d_in[12];
    const float* b2 = (const float*)d_in[13];
    const float* g2 = (const float*)d_in[14];
    const float* be2 = (const float*)d_in[15];
    const float* g3 = (const float*)d_in[16];
    const float* be3 = (const float*)d_in[17];

    // workspace map (peak ~124 MiB), per-batch pipeline with aliasing:
    //  [0,32M)      videoBF (alive whole loop)
    //  [32M,40M)    K_b bf16        -> XBF_b (after xk passes)
    //  [40M,48M)    V_b bf16        -> F_b (FF2 out)
    //  [48M,56M)    VT_b bf16       -> Y_b (attn@Wo out)
    //  [56M,89.5M)  KP (33.5M)      -> XP (q-side) -> H_b (FFN hidden, 32M)
    //  [90.5,91M)   ctxT_b bf16
    //  [91M,92M)    smalls: diagK, ksum, denom, kmax16, projBF
    //  [92M,100M)   ctx partials fp32 [8][16][256][64] -> OUT_b bf16 (sequential reuse)
    //  [100M,124M)  weights bf16: Wq,Wk,Wv,Wo (2M ea), W1 (8M), W2 (8M)
    //  d_out: Q fp32 (all batches) -> X_b fp32 -> final out
    char* ws = (char*)d_ws;
    const size_t MB = 1048576ull;
    ushort_t* videoBF = (ushort_t*)(ws + 0);
    ushort_t* Kb   = (ushort_t*)(ws + 32 * MB);
    ushort_t* XBFb = (ushort_t*)(ws + 32 * MB);
    ushort_t* Vb   = (ushort_t*)(ws + 40 * MB);
    ushort_t* Fb   = (ushort_t*)(ws + 40 * MB);
    ushort_t* VTb  = (ushort_t*)(ws + 48 * MB);
    ushort_t* Yb   = (ushort_t*)(ws + 48 * MB);
    ushort_t* KP   = (ushort_t*)(ws + 56 * MB);   // also XP, then H_b
    ushort_t* Hb   = (ushort_t*)(ws + 56 * MB);
    ushort_t* ctxTb = (ushort_t*)(ws + 93847552ull + MB);   // 90.5 MB
    char* smalls = ws + 91 * MB + 393216ull;                // 91.375 MB
    float*    diagK  = (float*)(smalls);                    // 256 KB
    float*    ksum   = (float*)(smalls + 262144);           // 16 KB
    float*    denomB = (float*)(smalls + 278528);           // 256 KB
    unsigned* kmax16 = (unsigned*)(smalls + 540672);        // 64 B
    ushort_t* projBF = (ushort_t*)(smalls + 541184);        // 32 KB
    float*    ctxp  = (float*)(ws + 92 * MB);               // 8 MB partials (dead before OUT)
    ushort_t* OUTb = (ushort_t*)(ws + 92 * MB);
    ushort_t* WqBF = (ushort_t*)(ws + 100 * MB);
    ushort_t* WkBF = (ushort_t*)(ws + 102 * MB);
    ushort_t* WvBF = (ushort_t*)(ws + 104 * MB);
    ushort_t* WoBF = (ushort_t*)(ws + 106 * MB);
    ushort_t* W1BF = (ushort_t*)(ws + 108 * MB);
    ushort_t* W2BF = (ushort_t*)(ws + 116 * MB);
    float* Qbuf = (float*)d_out;

    dim3 blk(256);

    // one-time fp32 -> bf16 conversions
    cvt_bf16<<<dim3(ROWS * DMODEL / 1024), blk, 0, stream>>>(video, videoBF, ROWS * DMODEL / 4);
    cvt_bf16<<<dim3(DMODEL * DMODEL / 1024), blk, 0, stream>>>(Wq, WqBF, DMODEL * DMODEL / 4);
    cvt_bf16<<<dim3(DMODEL * DMODEL / 1024), blk, 0, stream>>>(Wk, WkBF, DMODEL * DMODEL / 4);
    cvt_bf16<<<dim3(DMODEL * DMODEL / 1024), blk, 0, stream>>>(Wv, WvBF, DMODEL * DMODEL / 4);
    cvt_bf16<<<dim3(DMODEL * DMODEL / 1024), blk, 0, stream>>>(Wo, WoBF, DMODEL * DMODEL / 4);
    cvt_bf16<<<dim3(DFF * DMODEL / 1024), blk, 0, stream>>>(W1, W1BF, DFF * DMODEL / 4);
    cvt_bf16<<<dim3(DFF * DMODEL / 1024), blk, 0, stream>>>(W2, W2BF, DFF * DMODEL / 4);
    cvt_bf16<<<dim3(16), blk, 0, stream>>>(proj, projBF, MFEAT * DH / 4);

    // Q projection, all rows (fp32 out into d_out)
    gemm_mfma<4, float><<<dim3(8, ROWS / 128), blk, 0, stream>>>(
        videoBF, WqBF, bq, Qbuf, DMODEL, DMODEL, 0);

    dim3 gP(8, 32);   // per-batch 4096-row projection grid

    for (int b = 0; b < BATCH; ++b) {
        const size_t roff = (size_t)b * N_TOK;
        const ushort_t* vbf = videoBF + roff * DMODEL;
        float* Qb = Qbuf + roff * DMODEL;

        // fused K+V projections (512 blocks)
        gemm_kv<<<dim3(16, 32), blk, 0, stream>>>(vbf, WkBF, WvBF, bk, bv, Kb, Vb);
        vt_kernel<<<dim3(64, 16), blk, 0, stream>>>(Vb, VTb);
        diagk_kernel<<<dim3(1024), blk, 0, stream>>>(Kb, diagK);

        hipMemsetAsync(kmax16, 0, 64, stream);

        // K-side features: max pass, then exp pass -> KP[h][m][n]
        xk_kernel<<<dim3(2, 32, 16), blk, 0, stream>>>(projBF, Kb, diagK, kmax16, KP, 0);
        xk_kernel<<<dim3(2, 32, 16), blk, 0, stream>>>(projBF, Kb, diagK, kmax16, KP, 1);
        ksum_kernel<<<dim3(1024), blk, 0, stream>>>(KP, ksum);
        ctx_mfma<<<dim3(8, 2, 16), blk, 0, stream>>>(KP, VTb, ctxp);
        ctx_transpose<<<dim3(64), blk, 0, stream>>>(ctxp, ctxTb);

        // Q-side (XP reuses the KP region)
        xp_gemm<<<dim3(2, 32, 16), blk, 0, stream>>>(Qb, projBF, KP);
        qp_kernel<<<dim3(2048), blk, 0, stream>>>(KP, Qb, ksum, denomB);
        out_gemm<<<dim3(32, 16), blk, 0, stream>>>(KP, ctxTb, denomB, OUTb);

        // Wo, LN1, FFN, LN2 (all per batch)
        gemm_mfma<4, ushort_t><<<gP, blk, 0, stream>>>(OUTb, WoBF, bo, Yb, DMODEL, DMODEL, 0);
        ln_kernel<<<dim3(N_TOK), blk, 0, stream>>>(
            video + roff * DMODEL, Yb, 1, g2, be2, Qb, XBFb);
        gemm_mfma<4, ushort_t><<<dim3(32, 32), blk, 0, stream>>>(
            XBFb, W1BF, b1, Hb, DFF, DMODEL, 1);
        gemm_mfma<2, ushort_t><<<dim3(16, 32), blk, 0, stream>>>(
            Hb, W2BF, b2, Fb, DMODEL, DFF, 0);
        ln_kernel<<<dim3(N_TOK), blk, 0, stream>>>(
            Qb, Fb, 1, g3, be3, Qb, nullptr);
    }
}